// Round 3
// baseline (1023.122 us; speedup 1.0000x reference)
//
#include <hip/hip_runtime.h>

#define T_STEPS 256
#define BATCH   128
#define DIM     1024
#define NROWS   (T_STEPS * BATCH)        // 32768 qx rows

#define NBLK    1024
#define NTHR    256

// role split within the single fused grid
#define PREP_BLKS 128                    // blocks 0..127: prep, then join qx
#define REC_BLK0  128                    // blocks 128..255: recurrence chains
#define QX_BLK0   256                    // blocks 256..1023: pure qx
#define QX_BLOCKS 896                    // 128 (post-prep) + 768
#define QX_WAVES  3584                   // QX_BLOCKS * 4
#define NITER     10                     // ceil(NROWS / QX_WAVES)

typedef float vfloat4 __attribute__((ext_vector_type(4)));  // nontemporal builtins

// ws float-offset layout
#define WS_M     0                        // float[4*1024]
#define WS_V     4096                     // float[4]
#define WS_CB    4128                     // float[4]
#define WS_C1    4136                     // unsigned: prep-done counter
#define WS_CNT   4140                     // unsigned[NITER]: qx chunk counters
#define WS_ZERO_BYTES (4152 * 4)          // memset covers M + v + cb + counters
#define WS_QX    8192                     // float4[32768]

// ---------------- sync helpers (device-scope, cross-XCD safe) ----------------
__device__ __forceinline__ void spin_geq(const unsigned* p, unsigned target) {
    // bounded spin so a logic bug produces a wrong answer, not a GPU hang
    for (int k = 0; k < (1 << 22); ++k) {
        if (__hip_atomic_load(p, __ATOMIC_ACQUIRE, __HIP_MEMORY_SCOPE_AGENT) >= target)
            return;
        __builtin_amdgcn_s_sleep(2);
    }
}

// all threads of the block wait until *p >= target, then invalidate caches
__device__ __forceinline__ void block_wait(const unsigned* p, unsigned target) {
    if (threadIdx.x == 0) spin_geq(p, target);
    __syncthreads();
    __threadfence();          // acquire: invalidate L1/L2 so fresh data is read
}

// all block stores are complete (syncthreads drains vmcnt) -> writeback + count
__device__ __forceinline__ void block_signal(unsigned* p) {
    __syncthreads();
    if (threadIdx.x == 0) {
        __threadfence();      // release: writeback dirty L2 lines
        atomicAdd(p, 1u);     // device-scope
    }
}

// ---------------- recurrence math ----------------
__device__ __forceinline__ float fast_tanh(float x) {
    float e = __expf(2.f * x);
    return (e - 1.f) * __builtin_amdgcn_rcpf(e + 1.f);
}

__device__ __forceinline__ void rec_step(float4 q,
                                         float b0, float b1, float b2, float b3,
                                         float v0, float v1, float v2, float v3,
                                         float& h, float& c) {
    float z0 = __cosf(q.x + b0 + h * v0);
    float z1 = __cosf(q.y + b1 + h * v1);
    float z2 = __cosf(q.z + b2 + h * v2);
    float z3 = __cosf(q.w + b3 + h * v3);
    float e1 = z0 * z1;
    float e2 = e1 * z2;
    float e3 = e2 * z3;
    float e0 = z1 * z2 * z3;
    float x0 = __expf(e0), x1 = __expf(e1), x2 = __expf(e2), x3 = __expf(e3);
    float inv = __builtin_amdgcn_rcpf(x0 + x1 + x2 + x3);
    float f  = x0 * inv;
    float i_ = x1 * inv;
    float g  = x2 * inv;
    float o  = x3 * inv;
    c = f * c + i_ * fast_tanh(g);
    h = o * fast_tanh(c);
}

// ---------------- the single fused kernel ----------------
__global__ __launch_bounds__(NTHR) void k_fused(
        const float* __restrict__ x,
        const float* __restrict__ Wi,
        const float* __restrict__ bi,
        const float* __restrict__ Wh,
        const float* __restrict__ bh,
        const float* __restrict__ Wq,
        const float* __restrict__ bq,
        const float* __restrict__ theta,
        float* __restrict__ ws,
        float* __restrict__ out)
{
    float*    M    = ws + WS_M;
    float*    v    = ws + WS_V;
    float*    cb   = ws + WS_CB;
    unsigned* c1   = (unsigned*)(ws + WS_C1);
    unsigned* cnt  = (unsigned*)(ws + WS_CNT);
    float4*   qx4  = (float4*)(ws + WS_QX);

    const int blk  = blockIdx.x;
    const int tid  = threadIdx.x;
    const int wave = tid >> 6;
    const int lane = tid & 63;

    // ============ phase 1: prep (blocks 0..127) ============
    if (blk < 64) {
        int j0 = blk * 16;
        #pragma unroll
        for (int db = 0; db < 4; db++) {
            int d = db * 256 + tid;
            float a0 = 0.f, a1 = 0.f, a2 = 0.f, a3 = 0.f;
            #pragma unroll 4
            for (int jj = 0; jj < 16; jj++) {
                int j = j0 + jj;
                float wv = Wi[(size_t)j * DIM + d];   // coalesced 1KB/instr
                a0 += Wq[0 * DIM + j] * wv;           // uniform -> scalar loads
                a1 += Wq[1 * DIM + j] * wv;
                a2 += Wq[2 * DIM + j] * wv;
                a3 += Wq[3 * DIM + j] * wv;
            }
            unsafeAtomicAdd(&M[0 * DIM + d], a0);
            unsafeAtomicAdd(&M[1 * DIM + d], a1);
            unsafeAtomicAdd(&M[2 * DIM + d], a2);
            unsafeAtomicAdd(&M[3 * DIM + d], a3);
        }
        block_signal(c1);
    } else if (blk < PREP_BLKS) {
        int j0 = (blk - 64) * 16 + wave * 4;
        float sv0 = 0.f, sv1 = 0.f, sv2 = 0.f, sv3 = 0.f;
        float sc0 = 0.f, sc1 = 0.f, sc2 = 0.f, sc3 = 0.f;
        #pragma unroll
        for (int jj = 0; jj < 4; jj++) {
            int j = j0 + jj;
            const float4* row = (const float4*)(Wh + (size_t)j * DIM);
            float s = 0.f;
            #pragma unroll
            for (int k = 0; k < 4; k++) {
                float4 t4 = row[k * 64 + lane];
                s += t4.x + t4.y + t4.z + t4.w;
            }
            #pragma unroll
            for (int off = 32; off; off >>= 1) s += __shfl_xor(s, off, 64);
            float bb = bi[j] + bh[j];
            float q0 = Wq[0 * DIM + j], q1 = Wq[1 * DIM + j];
            float q2 = Wq[2 * DIM + j], q3 = Wq[3 * DIM + j];
            sv0 += q0 * s;  sc0 += q0 * bb;
            sv1 += q1 * s;  sc1 += q1 * bb;
            sv2 += q2 * s;  sc2 += q2 * bb;
            sv3 += q3 * s;  sc3 += q3 * bb;
        }
        if (lane == 0) {
            unsafeAtomicAdd(&v[0], sv0);  unsafeAtomicAdd(&v[1], sv1);
            unsafeAtomicAdd(&v[2], sv2);  unsafeAtomicAdd(&v[3], sv3);
            unsafeAtomicAdd(&cb[0], sc0); unsafeAtomicAdd(&cb[1], sc1);
            unsafeAtomicAdd(&cb[2], sc2); unsafeAtomicAdd(&cb[3], sc3);
        }
        block_signal(c1);
    }

    // ============ recurrence blocks (128..255): stream under qx ============
    if (blk >= REC_BLK0 && blk < REC_BLK0 + BATCH) {
        block_wait(c1, PREP_BLKS);               // v, cb ready
        const int b    = blk - REC_BLK0;
        const int foff = wave * 256 + lane * 4;  // quarter-row this wave stores

        float v0 = v[0], v1 = v[1], v2 = v[2], v3 = v[3];
        float b0 = cb[0] + bq[0] + theta[0];
        float b1 = cb[1] + bq[1] + theta[1];
        float b2 = cb[2] + bq[2] + theta[2];
        float b3 = cb[3] + bq[3] + theta[3];

        float h = 0.f, c = 0.f;
        float4 q0, q1, q2, q3, q4, q5, q6, q7;

        #define EMIT_H(tt)                                                          \
            do {                                                                    \
                vfloat4 vv = {h, h, h, h};                                          \
                __builtin_nontemporal_store(vv,                                     \
                    (vfloat4*)(out + ((size_t)(tt) * BATCH + b) * DIM + foff));     \
            } while (0)

        for (int gt = 0; gt < T_STEPS / 32; ++gt) {
            // rows needed for this 32-step group + 8-step prefetch lookahead
            int r_hi = (gt * 32 + 40) * BATCH;
            if (r_hi > NROWS) r_hi = NROWS;
            int g = (r_hi + QX_WAVES - 1) / QX_WAVES - 1;   // covering chunk
            if (g >= NITER) g = NITER - 1;
            block_wait(&cnt[g], QX_BLOCKS);

            if (gt == 0) {                       // preload first 8 steps
                q0 = qx4[0 * BATCH + b]; q1 = qx4[1 * BATCH + b];
                q2 = qx4[2 * BATCH + b]; q3 = qx4[3 * BATCH + b];
                q4 = qx4[4 * BATCH + b]; q5 = qx4[5 * BATCH + b];
                q6 = qx4[6 * BATCH + b]; q7 = qx4[7 * BATCH + b];
            }
            for (int t = gt * 32; t < gt * 32 + 32; t += 8) {
                float4 n0, n1, n2, n3, n4, n5, n6, n7;
                if (t + 8 < T_STEPS) {           // prefetch next 8 (issued up front)
                    n0 = qx4[(t + 8)  * BATCH + b];  n1 = qx4[(t + 9)  * BATCH + b];
                    n2 = qx4[(t + 10) * BATCH + b];  n3 = qx4[(t + 11) * BATCH + b];
                    n4 = qx4[(t + 12) * BATCH + b];  n5 = qx4[(t + 13) * BATCH + b];
                    n6 = qx4[(t + 14) * BATCH + b];  n7 = qx4[(t + 15) * BATCH + b];
                }
                rec_step(q0, b0, b1, b2, b3, v0, v1, v2, v3, h, c); EMIT_H(t + 0);
                rec_step(q1, b0, b1, b2, b3, v0, v1, v2, v3, h, c); EMIT_H(t + 1);
                rec_step(q2, b0, b1, b2, b3, v0, v1, v2, v3, h, c); EMIT_H(t + 2);
                rec_step(q3, b0, b1, b2, b3, v0, v1, v2, v3, h, c); EMIT_H(t + 3);
                rec_step(q4, b0, b1, b2, b3, v0, v1, v2, v3, h, c); EMIT_H(t + 4);
                rec_step(q5, b0, b1, b2, b3, v0, v1, v2, v3, h, c); EMIT_H(t + 5);
                rec_step(q6, b0, b1, b2, b3, v0, v1, v2, v3, h, c); EMIT_H(t + 6);
                rec_step(q7, b0, b1, b2, b3, v0, v1, v2, v3, h, c); EMIT_H(t + 7);
                q0 = n0; q1 = n1; q2 = n2; q3 = n3; q4 = n4; q5 = n5; q6 = n6; q7 = n7;
            }
        }
        #undef EMIT_H

        // tail rows: hx broadcast = final h; cx broadcast = final c
        vfloat4 hv = {h, h, h, h};
        vfloat4 cv = {c, c, c, c};
        __builtin_nontemporal_store(hv,
            (vfloat4*)(out + ((size_t)NROWS + b) * DIM + foff));
        __builtin_nontemporal_store(cv,
            (vfloat4*)(out + ((size_t)NROWS + BATCH + b) * DIM + foff));
        return;
    }

    // ============ qx blocks: 0..127 (after prep) and 256..1023 ============
    block_wait(c1, PREP_BLKS);                   // M complete

    const int qxw = (blk < PREP_BLKS) ? (blk * 4 + wave)
                                      : (512 + (blk - QX_BLK0) * 4 + wave);

    float4 m[4][4];                              // M fragment in regs
    #pragma unroll
    for (int w = 0; w < 4; w++)
        #pragma unroll
        for (int k = 0; k < 4; k++)
            m[w][k] = *(const float4*)(M + w * DIM + k * 256 + lane * 4);

    for (int g = 0; g < NITER; ++g) {
        int r = qxw + g * QX_WAVES;
        if (r < NROWS) {
            const float4* row = (const float4*)(x + (size_t)r * DIM);
            float a0 = 0.f, a1 = 0.f, a2 = 0.f, a3 = 0.f;
            #pragma unroll
            for (int k = 0; k < 4; k++) {
                float4 xv = row[k * 64 + lane];  // contiguous 1 KB/instr
                a0 += xv.x * m[0][k].x + xv.y * m[0][k].y + xv.z * m[0][k].z + xv.w * m[0][k].w;
                a1 += xv.x * m[1][k].x + xv.y * m[1][k].y + xv.z * m[1][k].z + xv.w * m[1][k].w;
                a2 += xv.x * m[2][k].x + xv.y * m[2][k].y + xv.z * m[2][k].z + xv.w * m[2][k].w;
                a3 += xv.x * m[3][k].x + xv.y * m[3][k].y + xv.z * m[3][k].z + xv.w * m[3][k].w;
            }
            #pragma unroll
            for (int off = 32; off; off >>= 1) {
                a0 += __shfl_xor(a0, off, 64);
                a1 += __shfl_xor(a1, off, 64);
                a2 += __shfl_xor(a2, off, 64);
                a3 += __shfl_xor(a3, off, 64);
            }
            if (lane == 0) qx4[r] = make_float4(a0, a1, a2, a3);
        }
        block_signal(&cnt[g]);                   // publish chunk g complete
    }
}

extern "C" void kernel_launch(void* const* d_in, const int* in_sizes, int n_in,
                              void* d_out, int out_size, void* d_ws, size_t ws_size,
                              hipStream_t stream) {
    const float* inputs = (const float*)d_in[0];
    const float* Wi     = (const float*)d_in[1];
    const float* bi     = (const float*)d_in[2];
    const float* Wh     = (const float*)d_in[3];
    const float* bh     = (const float*)d_in[4];
    const float* Wq     = (const float*)d_in[5];
    const float* bq     = (const float*)d_in[6];
    const float* theta  = (const float*)d_in[7];
    float* out = (float*)d_out;
    float* ws  = (float*)d_ws;

    (void)hipMemsetAsync(ws, 0, WS_ZERO_BYTES, stream);   // zero M+v+cb+counters

    k_fused<<<NBLK, NTHR, 0, stream>>>(inputs, Wi, bi, Wh, bh, Wq, bq, theta, ws, out);
}

// Round 4
// 460.493 us; speedup vs baseline: 2.2218x; 2.2218x over previous
//
#include <hip/hip_runtime.h>

#define T_STEPS 256
#define BATCH   128
#define DIM     1024
#define NROWS   (T_STEPS * BATCH)        // 32768 qx rows

#define NBLK    1024
#define NTHR    256
#define REC_BLKS 128                     // blocks 0..127: one chain per block
#define QX_BLKS  (NBLK - REC_BLKS)       // 896 qx blocks
#define QX_WAVES (QX_BLKS * 4)           // 3584 qx waves
#define NITER    ((NROWS + QX_WAVES - 1) / QX_WAVES)   // 10 chunks

typedef float vfloat4 __attribute__((ext_vector_type(4)));  // nontemporal builtins

// ws float-offset layout
#define WS_M     0                        // float[4*1024]
#define WS_V     4096                     // float[4]
#define WS_CB    4128                     // float[4]
#define WS_CNT   4136                     // unsigned[NITER] chunk counters
#define WS_ZERO_BYTES ((WS_CNT + NITER) * 4)
#define WS_QX    8192                     // float4[32768]

// ---------- prep: M = Wq@Wi via fp32 HW atomics; v/cb via atomics (proven) ----------
__global__ __launch_bounds__(256) void k_prep(const float* __restrict__ Wi,
                                              const float* __restrict__ Wh,
                                              const float* __restrict__ bi,
                                              const float* __restrict__ bh,
                                              const float* __restrict__ Wq,
                                              float* __restrict__ M,
                                              float* __restrict__ v,
                                              float* __restrict__ cb) {
    int blk  = blockIdx.x;
    int tid  = threadIdx.x;
    int wave = tid >> 6;
    int lane = tid & 63;

    if (blk < 64) {
        int j0 = blk * 16;
        #pragma unroll
        for (int db = 0; db < 4; db++) {
            int d = db * 256 + tid;
            float a0 = 0.f, a1 = 0.f, a2 = 0.f, a3 = 0.f;
            #pragma unroll 4
            for (int jj = 0; jj < 16; jj++) {
                int j = j0 + jj;
                float wv = Wi[(size_t)j * DIM + d];   // coalesced 1KB/instr
                a0 += Wq[0 * DIM + j] * wv;           // uniform -> scalar loads
                a1 += Wq[1 * DIM + j] * wv;
                a2 += Wq[2 * DIM + j] * wv;
                a3 += Wq[3 * DIM + j] * wv;
            }
            unsafeAtomicAdd(&M[0 * DIM + d], a0);
            unsafeAtomicAdd(&M[1 * DIM + d], a1);
            unsafeAtomicAdd(&M[2 * DIM + d], a2);
            unsafeAtomicAdd(&M[3 * DIM + d], a3);
        }
    } else {
        int j0 = (blk - 64) * 16 + wave * 4;
        float sv0 = 0.f, sv1 = 0.f, sv2 = 0.f, sv3 = 0.f;
        float sc0 = 0.f, sc1 = 0.f, sc2 = 0.f, sc3 = 0.f;
        #pragma unroll
        for (int jj = 0; jj < 4; jj++) {
            int j = j0 + jj;
            const float4* row = (const float4*)(Wh + (size_t)j * DIM);
            float s = 0.f;
            #pragma unroll
            for (int k = 0; k < 4; k++) {
                float4 t4 = row[k * 64 + lane];
                s += t4.x + t4.y + t4.z + t4.w;
            }
            #pragma unroll
            for (int off = 32; off; off >>= 1) s += __shfl_xor(s, off, 64);
            float bb = bi[j] + bh[j];
            float q0 = Wq[0 * DIM + j], q1 = Wq[1 * DIM + j];
            float q2 = Wq[2 * DIM + j], q3 = Wq[3 * DIM + j];
            sv0 += q0 * s;  sc0 += q0 * bb;
            sv1 += q1 * s;  sc1 += q1 * bb;
            sv2 += q2 * s;  sc2 += q2 * bb;
            sv3 += q3 * s;  sc3 += q3 * bb;
        }
        if (lane == 0) {
            unsafeAtomicAdd(&v[0], sv0);  unsafeAtomicAdd(&v[1], sv1);
            unsafeAtomicAdd(&v[2], sv2);  unsafeAtomicAdd(&v[3], sv3);
            unsafeAtomicAdd(&cb[0], sc0); unsafeAtomicAdd(&cb[1], sc1);
            unsafeAtomicAdd(&cb[2], sc2); unsafeAtomicAdd(&cb[3], sc3);
        }
    }
}

// ---------------- recurrence math ----------------
__device__ __forceinline__ float fast_tanh(float x) {
    float e = __expf(2.f * x);
    return (e - 1.f) * __builtin_amdgcn_rcpf(e + 1.f);
}

__device__ __forceinline__ void rec_step(float4 q,
                                         float b0, float b1, float b2, float b3,
                                         float v0, float v1, float v2, float v3,
                                         float& h, float& c) {
    float z0 = __cosf(q.x + b0 + h * v0);
    float z1 = __cosf(q.y + b1 + h * v1);
    float z2 = __cosf(q.z + b2 + h * v2);
    float z3 = __cosf(q.w + b3 + h * v3);
    float e1 = z0 * z1;
    float e2 = e1 * z2;
    float e3 = e2 * z3;
    float e0 = z1 * z2 * z3;
    float x0 = __expf(e0), x1 = __expf(e1), x2 = __expf(e2), x3 = __expf(e3);
    float inv = __builtin_amdgcn_rcpf(x0 + x1 + x2 + x3);
    float f  = x0 * inv;
    float i_ = x1 * inv;
    float g  = x2 * inv;
    float o  = x3 * inv;
    c = f * c + i_ * fast_tanh(g);
    h = o * fast_tanh(c);
}

// relaxed agent-scope spin: NO per-iteration cache maintenance (the round-3 killer).
// sc-flagged load reads the device coherence point directly.
__device__ __forceinline__ void wait_cnt(const unsigned* p, unsigned target) {
    if (threadIdx.x == 0) {
        for (int k = 0; k < (1 << 20); ++k) {   // bounded: bug -> wrong, not hang
            if (__hip_atomic_load(p, __ATOMIC_RELAXED, __HIP_MEMORY_SCOPE_AGENT) >= target)
                break;
            __builtin_amdgcn_s_sleep(8);
        }
    }
    __syncthreads();
    asm volatile("" ::: "memory");              // compiler barrier only
}

// ---------------- fused qx + recurrence + write ----------------
__global__ __launch_bounds__(NTHR) void k_main(const float* __restrict__ x,
                                               const float* __restrict__ bq,
                                               const float* __restrict__ theta,
                                               const float* __restrict__ v,
                                               const float* __restrict__ cbp,
                                               float* __restrict__ ws,
                                               float* __restrict__ out)
{
    float*    M   = ws + WS_M;
    unsigned* cnt = (unsigned*)(ws + WS_CNT);
    float4*   qx4 = (float4*)(ws + WS_QX);

    const int blk  = blockIdx.x;
    const int tid  = threadIdx.x;
    const int wave = tid >> 6;
    const int lane = tid & 63;

    if (blk >= REC_BLKS) {
        // ---------- qx producer: wait-free, retires unconditionally ----------
        const int w = (blk - REC_BLKS) * 4 + wave;

        float4 m[4][4];                              // M fragment in regs
        #pragma unroll
        for (int ww = 0; ww < 4; ww++)
            #pragma unroll
            for (int k = 0; k < 4; k++)
                m[ww][k] = *(const float4*)(M + ww * DIM + k * 256 + lane * 4);

        for (int g = 0; g < NITER; ++g) {
            int r = w + g * QX_WAVES;
            if (r < NROWS) {
                const float4* row = (const float4*)(x + (size_t)r * DIM);
                float a0 = 0.f, a1 = 0.f, a2 = 0.f, a3 = 0.f;
                #pragma unroll
                for (int k = 0; k < 4; k++) {
                    float4 xv = row[k * 64 + lane];  // contiguous 1 KB/instr
                    a0 += xv.x * m[0][k].x + xv.y * m[0][k].y + xv.z * m[0][k].z + xv.w * m[0][k].w;
                    a1 += xv.x * m[1][k].x + xv.y * m[1][k].y + xv.z * m[1][k].z + xv.w * m[1][k].w;
                    a2 += xv.x * m[2][k].x + xv.y * m[2][k].y + xv.z * m[2][k].z + xv.w * m[2][k].w;
                    a3 += xv.x * m[3][k].x + xv.y * m[3][k].y + xv.z * m[3][k].z + xv.w * m[3][k].w;
                }
                #pragma unroll
                for (int off = 32; off; off >>= 1) {
                    a0 += __shfl_xor(a0, off, 64);
                    a1 += __shfl_xor(a1, off, 64);
                    a2 += __shfl_xor(a2, off, 64);
                    a3 += __shfl_xor(a3, off, 64);
                }
                if (lane == 0) {
                    // agent-scope stores: bypass L1/L2, land at coherence point.
                    unsigned long long lo = (unsigned long long)__float_as_uint(a0)
                                          | ((unsigned long long)__float_as_uint(a1) << 32);
                    unsigned long long hi = (unsigned long long)__float_as_uint(a2)
                                          | ((unsigned long long)__float_as_uint(a3) << 32);
                    unsigned long long* p = (unsigned long long*)&qx4[r];
                    __hip_atomic_store(p,     lo, __ATOMIC_RELAXED, __HIP_MEMORY_SCOPE_AGENT);
                    __hip_atomic_store(p + 1, hi, __ATOMIC_RELAXED, __HIP_MEMORY_SCOPE_AGENT);
                }
            }
            // __syncthreads drains vmcnt (stores acked from coherence point)
            __syncthreads();
            if (tid == 0)
                __hip_atomic_fetch_add(&cnt[g], 1u, __ATOMIC_RELAXED, __HIP_MEMORY_SCOPE_AGENT);
        }
        return;
    }

    // ---------- rec consumer: block b = blk, full-row writes ----------
    const int b = blk;

    float v0 = v[0], v1 = v[1], v2 = v[2], v3 = v[3];
    float b0 = cbp[0] + bq[0] + theta[0];
    float b1 = cbp[1] + bq[1] + theta[1];
    float b2 = cbp[2] + bq[2] + theta[2];
    float b3 = cbp[3] + bq[3] + theta[3];

    float h = 0.f, c = 0.f;

    #define EMIT_H(tt)                                                      \
        do {                                                                \
            vfloat4 vv = {h, h, h, h};                                      \
            __builtin_nontemporal_store(vv,                                 \
                (vfloat4*)(out + ((size_t)(tt) * BATCH + b) * DIM) + tid);  \
        } while (0)

    // chunk 0 covers rows 0..3583 -> enough for the first 8-step preload
    wait_cnt(&cnt[0], QX_BLKS);

    float4 q0 = qx4[0 * BATCH + b], q1 = qx4[1 * BATCH + b];
    float4 q2 = qx4[2 * BATCH + b], q3 = qx4[3 * BATCH + b];
    float4 q4 = qx4[4 * BATCH + b], q5 = qx4[5 * BATCH + b];
    float4 q6 = qx4[6 * BATCH + b], q7 = qx4[7 * BATCH + b];

    for (int t = 0; t < T_STEPS; t += 8) {
        float4 n0, n1, n2, n3, n4, n5, n6, n7;
        if (t + 8 < T_STEPS) {
            // prefetch rows [(t+8)*128, (t+16)*128); wait for covering chunk
            int last_row = (t + 16) * BATCH - 1;
            if (last_row >= NROWS) last_row = NROWS - 1;
            wait_cnt(&cnt[last_row / QX_WAVES], QX_BLKS);
            n0 = qx4[(t + 8)  * BATCH + b];  n1 = qx4[(t + 9)  * BATCH + b];
            n2 = qx4[(t + 10) * BATCH + b];  n3 = qx4[(t + 11) * BATCH + b];
            n4 = qx4[(t + 12) * BATCH + b];  n5 = qx4[(t + 13) * BATCH + b];
            n6 = qx4[(t + 14) * BATCH + b];  n7 = qx4[(t + 15) * BATCH + b];
        }
        rec_step(q0, b0, b1, b2, b3, v0, v1, v2, v3, h, c); EMIT_H(t + 0);
        rec_step(q1, b0, b1, b2, b3, v0, v1, v2, v3, h, c); EMIT_H(t + 1);
        rec_step(q2, b0, b1, b2, b3, v0, v1, v2, v3, h, c); EMIT_H(t + 2);
        rec_step(q3, b0, b1, b2, b3, v0, v1, v2, v3, h, c); EMIT_H(t + 3);
        rec_step(q4, b0, b1, b2, b3, v0, v1, v2, v3, h, c); EMIT_H(t + 4);
        rec_step(q5, b0, b1, b2, b3, v0, v1, v2, v3, h, c); EMIT_H(t + 5);
        rec_step(q6, b0, b1, b2, b3, v0, v1, v2, v3, h, c); EMIT_H(t + 6);
        rec_step(q7, b0, b1, b2, b3, v0, v1, v2, v3, h, c); EMIT_H(t + 7);
        q0 = n0; q1 = n1; q2 = n2; q3 = n3; q4 = n4; q5 = n5; q6 = n6; q7 = n7;
    }
    #undef EMIT_H

    // tail rows: hx broadcast = final h; cx broadcast = final c (full rows)
    vfloat4 hv = {h, h, h, h};
    vfloat4 cv = {c, c, c, c};
    __builtin_nontemporal_store(hv, (vfloat4*)(out + ((size_t)NROWS + b) * DIM) + tid);
    __builtin_nontemporal_store(cv, (vfloat4*)(out + ((size_t)NROWS + BATCH + b) * DIM) + tid);
}

extern "C" void kernel_launch(void* const* d_in, const int* in_sizes, int n_in,
                              void* d_out, int out_size, void* d_ws, size_t ws_size,
                              hipStream_t stream) {
    const float* inputs = (const float*)d_in[0];
    const float* Wi     = (const float*)d_in[1];
    const float* bi     = (const float*)d_in[2];
    const float* Wh     = (const float*)d_in[3];
    const float* bh     = (const float*)d_in[4];
    const float* Wq     = (const float*)d_in[5];
    const float* bq     = (const float*)d_in[6];
    const float* theta  = (const float*)d_in[7];
    float* out = (float*)d_out;
    float* ws  = (float*)d_ws;

    float* M  = ws + WS_M;
    float* v  = ws + WS_V;
    float* cb = ws + WS_CB;

    (void)hipMemsetAsync(ws, 0, WS_ZERO_BYTES, stream);   // zero M + v + cb + cnt

    k_prep<<<128,  256, 0, stream>>>(Wi, Wh, bi, bh, Wq, M, v, cb);
    k_main<<<NBLK, 256, 0, stream>>>(inputs, bq, theta, v, cb, ws, out);
}

// Round 5
// 318.449 us; speedup vs baseline: 3.2128x; 1.4461x over previous
//
#include <hip/hip_runtime.h>

#define T_STEPS 256
#define BATCH   128
#define DIM     1024
#define NROWS   (T_STEPS * BATCH)        // 32768 qx rows

typedef float vfloat4 __attribute__((ext_vector_type(4)));  // nontemporal builtins

// ws float-offset layout (no memset needed: every cell is written before read)
#define WS_M     0                        // float[4*1024]   M = Wq@Wi
#define WS_VP    4096                     // float[64*8]     per-block {sv0..3, sc0..3}
#define WS_QX    8192                     // float4[32768]

// ---------- prep: atomic-free. blocks 0..15: M by column ownership;
//            blocks 16..79: Wh rowsum/cb partials -> vpart ----------
__global__ __launch_bounds__(256) void k_prep(const float* __restrict__ Wi,
                                              const float* __restrict__ Wh,
                                              const float* __restrict__ bi,
                                              const float* __restrict__ bh,
                                              const float* __restrict__ Wq,
                                              float* __restrict__ M,
                                              float* __restrict__ vpart) {
    int blk  = blockIdx.x;
    int tid  = threadIdx.x;
    int wave = tid >> 6;
    int lane = tid & 63;

    if (blk < 16) {
        // M[w][d] = sum_j Wq[w][j] * Wi[j][d]; block owns d in [blk*64, +64),
        // wave w owns output row w. Wq loads are wave-uniform -> scalar.
        int d = blk * 64 + lane;
        const float* wq = Wq + wave * DIM;
        float acc = 0.f;
        for (int j = 0; j < DIM; j += 8) {
            #pragma unroll
            for (int u = 0; u < 8; u++)
                acc += wq[j + u] * Wi[(size_t)(j + u) * DIM + d];
        }
        M[wave * DIM + d] = acc;
    } else {
        // Wh rowsums + bias terms; each wave handles 4 rows, partials via LDS.
        int bb = blk - 16;                    // 0..63
        __shared__ float red[4][8];
        int j0 = bb * 16 + wave * 4;
        float sv0 = 0.f, sv1 = 0.f, sv2 = 0.f, sv3 = 0.f;
        float sc0 = 0.f, sc1 = 0.f, sc2 = 0.f, sc3 = 0.f;
        #pragma unroll
        for (int jj = 0; jj < 4; jj++) {
            int j = j0 + jj;
            const float4* row = (const float4*)(Wh + (size_t)j * DIM);
            float s = 0.f;
            #pragma unroll
            for (int k = 0; k < 4; k++) {
                float4 t4 = row[k * 64 + lane];
                s += t4.x + t4.y + t4.z + t4.w;
            }
            #pragma unroll
            for (int off = 32; off; off >>= 1) s += __shfl_xor(s, off, 64);
            float bbias = bi[j] + bh[j];
            float q0 = Wq[0 * DIM + j], q1 = Wq[1 * DIM + j];
            float q2 = Wq[2 * DIM + j], q3 = Wq[3 * DIM + j];
            sv0 += q0 * s;  sc0 += q0 * bbias;
            sv1 += q1 * s;  sc1 += q1 * bbias;
            sv2 += q2 * s;  sc2 += q2 * bbias;
            sv3 += q3 * s;  sc3 += q3 * bbias;
        }
        if (lane == 0) {
            red[wave][0] = sv0; red[wave][1] = sv1; red[wave][2] = sv2; red[wave][3] = sv3;
            red[wave][4] = sc0; red[wave][5] = sc1; red[wave][6] = sc2; red[wave][7] = sc3;
        }
        __syncthreads();
        if (tid < 8)
            vpart[bb * 8 + tid] = red[0][tid] + red[1][tid] + red[2][tid] + red[3][tid];
    }
}

// ---------- qx = inputs @ M.T  [T*B, 4]; wave per row (proven) ----------
__global__ __launch_bounds__(256) void k_qx(const float* __restrict__ x,
                                            const float* __restrict__ M,
                                            float4* __restrict__ qx4) {
    int gtid   = blockIdx.x * blockDim.x + threadIdx.x;
    int wave   = gtid >> 6;
    int lane   = threadIdx.x & 63;
    int nwaves = (gridDim.x * blockDim.x) >> 6;

    float4 m[4][4];                                    // M fragment in regs
    #pragma unroll
    for (int w = 0; w < 4; w++)
        #pragma unroll
        for (int k = 0; k < 4; k++)
            m[w][k] = *(const float4*)(M + w * DIM + k * 256 + lane * 4);

    for (int r = wave; r < NROWS; r += nwaves) {
        const float4* row = (const float4*)(x + (size_t)r * DIM);
        float a0 = 0.f, a1 = 0.f, a2 = 0.f, a3 = 0.f;
        #pragma unroll
        for (int k = 0; k < 4; k++) {
            float4 xv = row[k * 64 + lane];            // contiguous 1 KB/instr
            a0 += xv.x * m[0][k].x + xv.y * m[0][k].y + xv.z * m[0][k].z + xv.w * m[0][k].w;
            a1 += xv.x * m[1][k].x + xv.y * m[1][k].y + xv.z * m[1][k].z + xv.w * m[1][k].w;
            a2 += xv.x * m[2][k].x + xv.y * m[2][k].y + xv.z * m[2][k].z + xv.w * m[2][k].w;
            a3 += xv.x * m[3][k].x + xv.y * m[3][k].y + xv.z * m[3][k].z + xv.w * m[3][k].w;
        }
        #pragma unroll
        for (int off = 32; off; off >>= 1) {
            a0 += __shfl_xor(a0, off, 64);
            a1 += __shfl_xor(a1, off, 64);
            a2 += __shfl_xor(a2, off, 64);
            a3 += __shfl_xor(a3, off, 64);
        }
        if (lane == 0) qx4[r] = make_float4(a0, a1, a2, a3);
    }
}

// ---------- recurrence + write: 512 blocks x 64 threads ----------
// Block (b, q): redundantly computes chain b (latency-bound -> redundancy is
// free) and writes quarter-row q (1 KB = 64 lanes x float4) of every output
// row. Write traffic spreads over all 256 CUs: floor ~20 us vs ~40 us at 128.
__device__ __forceinline__ float fast_tanh(float x) {
    float e = __expf(2.f * x);
    return (e - 1.f) * __builtin_amdgcn_rcpf(e + 1.f);
}

__device__ __forceinline__ void rec_step(float4 qv,
                                         float b0, float b1, float b2, float b3,
                                         float v0, float v1, float v2, float v3,
                                         float& h, float& c) {
    float z0 = __cosf(qv.x + b0 + h * v0);
    float z1 = __cosf(qv.y + b1 + h * v1);
    float z2 = __cosf(qv.z + b2 + h * v2);
    float z3 = __cosf(qv.w + b3 + h * v3);
    float e1 = z0 * z1;
    float e2 = e1 * z2;
    float e3 = e2 * z3;
    float e0 = z1 * z2 * z3;
    float x0 = __expf(e0), x1 = __expf(e1), x2 = __expf(e2), x3 = __expf(e3);
    float inv = __builtin_amdgcn_rcpf(x0 + x1 + x2 + x3);
    float f  = x0 * inv;
    float i_ = x1 * inv;
    float g  = x2 * inv;
    float o  = x3 * inv;
    c = f * c + i_ * fast_tanh(g);
    h = o * fast_tanh(c);
}

__global__ __launch_bounds__(64) void k_recw(const float* __restrict__ bq,
                                             const float* __restrict__ theta,
                                             const float* __restrict__ ws,
                                             float* __restrict__ out) {
    const float4* qx4 = (const float4*)(ws + WS_QX);
    const float4* vp4 = (const float4*)(ws + WS_VP);

    const int b    = blockIdx.x & 127;        // chain
    const int q    = blockIdx.x >> 7;         // quarter-row 0..3
    const int lane = threadIdx.x;             // 0..63

    // reduce the 64 vpart blocks lane-parallel: lane l holds block l's partials
    float4 sa = vp4[lane * 2];                // {sv0..3}
    float4 sc = vp4[lane * 2 + 1];            // {sc0..3}
    #pragma unroll
    for (int off = 32; off; off >>= 1) {
        sa.x += __shfl_xor(sa.x, off, 64);  sa.y += __shfl_xor(sa.y, off, 64);
        sa.z += __shfl_xor(sa.z, off, 64);  sa.w += __shfl_xor(sa.w, off, 64);
        sc.x += __shfl_xor(sc.x, off, 64);  sc.y += __shfl_xor(sc.y, off, 64);
        sc.z += __shfl_xor(sc.z, off, 64);  sc.w += __shfl_xor(sc.w, off, 64);
    }
    const float v0 = sa.x, v1 = sa.y, v2 = sa.z, v3 = sa.w;
    const float b0 = sc.x + bq[0] + theta[0];
    const float b1 = sc.y + bq[1] + theta[1];
    const float b2 = sc.z + bq[2] + theta[2];
    const float b3 = sc.w + bq[3] + theta[3];

    float h = 0.f, c = 0.f;

    #define EMIT_H(tt)                                                           \
        do {                                                                     \
            vfloat4 vv = {h, h, h, h};                                           \
            __builtin_nontemporal_store(vv,                                      \
                (vfloat4*)(out + ((size_t)(tt) * BATCH + b) * DIM + q * 256)     \
                    + lane);                                                     \
        } while (0)

    // preload first 8 steps (uniform-address loads -> broadcast, L2-hot)
    float4 q0 = qx4[0 * BATCH + b], q1 = qx4[1 * BATCH + b];
    float4 q2 = qx4[2 * BATCH + b], q3 = qx4[3 * BATCH + b];
    float4 q4 = qx4[4 * BATCH + b], q5 = qx4[5 * BATCH + b];
    float4 q6 = qx4[6 * BATCH + b], q7 = qx4[7 * BATCH + b];

    for (int t = 0; t < T_STEPS; t += 8) {
        float4 n0, n1, n2, n3, n4, n5, n6, n7;
        if (t + 8 < T_STEPS) {               // prefetch next 8 (issued up front)
            n0 = qx4[(t + 8)  * BATCH + b];  n1 = qx4[(t + 9)  * BATCH + b];
            n2 = qx4[(t + 10) * BATCH + b];  n3 = qx4[(t + 11) * BATCH + b];
            n4 = qx4[(t + 12) * BATCH + b];  n5 = qx4[(t + 13) * BATCH + b];
            n6 = qx4[(t + 14) * BATCH + b];  n7 = qx4[(t + 15) * BATCH + b];
        }
        rec_step(q0, b0, b1, b2, b3, v0, v1, v2, v3, h, c); EMIT_H(t + 0);
        rec_step(q1, b0, b1, b2, b3, v0, v1, v2, v3, h, c); EMIT_H(t + 1);
        rec_step(q2, b0, b1, b2, b3, v0, v1, v2, v3, h, c); EMIT_H(t + 2);
        rec_step(q3, b0, b1, b2, b3, v0, v1, v2, v3, h, c); EMIT_H(t + 3);
        rec_step(q4, b0, b1, b2, b3, v0, v1, v2, v3, h, c); EMIT_H(t + 4);
        rec_step(q5, b0, b1, b2, b3, v0, v1, v2, v3, h, c); EMIT_H(t + 5);
        rec_step(q6, b0, b1, b2, b3, v0, v1, v2, v3, h, c); EMIT_H(t + 6);
        rec_step(q7, b0, b1, b2, b3, v0, v1, v2, v3, h, c); EMIT_H(t + 7);
        q0 = n0; q1 = n1; q2 = n2; q3 = n3; q4 = n4; q5 = n5; q6 = n6; q7 = n7;
    }
    #undef EMIT_H

    // tail rows: hx broadcast = final h; cx broadcast = final c (quarter rows)
    vfloat4 hv = {h, h, h, h};
    vfloat4 cv = {c, c, c, c};
    __builtin_nontemporal_store(hv,
        (vfloat4*)(out + ((size_t)NROWS + b) * DIM + q * 256) + lane);
    __builtin_nontemporal_store(cv,
        (vfloat4*)(out + ((size_t)NROWS + BATCH + b) * DIM + q * 256) + lane);
}

extern "C" void kernel_launch(void* const* d_in, const int* in_sizes, int n_in,
                              void* d_out, int out_size, void* d_ws, size_t ws_size,
                              hipStream_t stream) {
    const float* inputs = (const float*)d_in[0];
    const float* Wi     = (const float*)d_in[1];
    const float* bi     = (const float*)d_in[2];
    const float* Wh     = (const float*)d_in[3];
    const float* bh     = (const float*)d_in[4];
    const float* Wq     = (const float*)d_in[5];
    const float* bq     = (const float*)d_in[6];
    const float* theta  = (const float*)d_in[7];
    float* out = (float*)d_out;
    float* ws  = (float*)d_ws;

    float*  M     = ws + WS_M;
    float*  vpart = ws + WS_VP;
    float4* qx4   = (float4*)(ws + WS_QX);

    // no memset: every ws cell is written before it is read (M by ownership,
    // vpart by plain stores, qx4 fully covered by k_qx)
    k_prep<<<80,   256, 0, stream>>>(Wi, Wh, bi, bh, Wq, M, vpart);
    k_qx  <<<1024, 256, 0, stream>>>(inputs, M, qx4);
    k_recw<<<512,  64,  0, stream>>>(bq, theta, ws, out);
}

// Round 6
// 305.196 us; speedup vs baseline: 3.3523x; 1.0434x over previous
//
#include <hip/hip_runtime.h>

#define T_STEPS 256
#define BATCH   128
#define DIM     1024
#define NROWS   (T_STEPS * BATCH)        // 32768 qx rows

typedef float vfloat4 __attribute__((ext_vector_type(4)));  // nontemporal builtins

// ws float-offset layout (no memset: every cell written before read)
#define WS_M     0                        // float[4*1024]   M = Wq@Wi
#define WS_VP    4096                     // float[64*8]     per-block {sv0..3, sc0..3}

// ---------- prep: atomic-free (proven R5). blocks 0..15: M by ownership;
//            blocks 16..79: Wh rowsum/cb partials -> vpart ----------
__global__ __launch_bounds__(256) void k_prep(const float* __restrict__ Wi,
                                              const float* __restrict__ Wh,
                                              const float* __restrict__ bi,
                                              const float* __restrict__ bh,
                                              const float* __restrict__ Wq,
                                              float* __restrict__ M,
                                              float* __restrict__ vpart) {
    int blk  = blockIdx.x;
    int tid  = threadIdx.x;
    int wave = tid >> 6;
    int lane = tid & 63;

    if (blk < 16) {
        // M[w][d] = sum_j Wq[w][j] * Wi[j][d]; block owns d in [blk*64, +64),
        // wave w owns output row w. Wq loads are wave-uniform -> scalar.
        int d = blk * 64 + lane;
        const float* wq = Wq + wave * DIM;
        float acc = 0.f;
        for (int j = 0; j < DIM; j += 8) {
            #pragma unroll
            for (int u = 0; u < 8; u++)
                acc += wq[j + u] * Wi[(size_t)(j + u) * DIM + d];
        }
        M[wave * DIM + d] = acc;
    } else {
        // Wh rowsums + bias terms; each wave handles 4 rows, partials via LDS.
        int bb = blk - 16;                    // 0..63
        __shared__ float red[4][8];
        int j0 = bb * 16 + wave * 4;
        float sv0 = 0.f, sv1 = 0.f, sv2 = 0.f, sv3 = 0.f;
        float sc0 = 0.f, sc1 = 0.f, sc2 = 0.f, sc3 = 0.f;
        #pragma unroll
        for (int jj = 0; jj < 4; jj++) {
            int j = j0 + jj;
            const float4* row = (const float4*)(Wh + (size_t)j * DIM);
            float s = 0.f;
            #pragma unroll
            for (int k = 0; k < 4; k++) {
                float4 t4 = row[k * 64 + lane];
                s += t4.x + t4.y + t4.z + t4.w;
            }
            #pragma unroll
            for (int off = 32; off; off >>= 1) s += __shfl_xor(s, off, 64);
            float bbias = bi[j] + bh[j];
            float q0 = Wq[0 * DIM + j], q1 = Wq[1 * DIM + j];
            float q2 = Wq[2 * DIM + j], q3 = Wq[3 * DIM + j];
            sv0 += q0 * s;  sc0 += q0 * bbias;
            sv1 += q1 * s;  sc1 += q1 * bbias;
            sv2 += q2 * s;  sc2 += q2 * bbias;
            sv3 += q3 * s;  sc3 += q3 * bbias;
        }
        if (lane == 0) {
            red[wave][0] = sv0; red[wave][1] = sv1; red[wave][2] = sv2; red[wave][3] = sv3;
            red[wave][4] = sc0; red[wave][5] = sc1; red[wave][6] = sc2; red[wave][7] = sc3;
        }
        __syncthreads();
        if (tid < 8)
            vpart[bb * 8 + tid] = red[0][tid] + red[1][tid] + red[2][tid] + red[3][tid];
    }
}

// ---------------- recurrence math ----------------
__device__ __forceinline__ float fast_tanh(float x) {
    float e = __expf(2.f * x);
    return (e - 1.f) * __builtin_amdgcn_rcpf(e + 1.f);
}

__device__ __forceinline__ void rec_step(float4 qv,
                                         float b0, float b1, float b2, float b3,
                                         float v0, float v1, float v2, float v3,
                                         float& h, float& c) {
    float z0 = __cosf(qv.x + b0 + h * v0);
    float z1 = __cosf(qv.y + b1 + h * v1);
    float z2 = __cosf(qv.z + b2 + h * v2);
    float z3 = __cosf(qv.w + b3 + h * v3);
    float e1 = z0 * z1;
    float e2 = e1 * z2;
    float e3 = e2 * z3;
    float e0 = z1 * z2 * z3;
    float x0 = __expf(e0), x1 = __expf(e1), x2 = __expf(e2), x3 = __expf(e3);
    float inv = __builtin_amdgcn_rcpf(x0 + x1 + x2 + x3);
    float f  = x0 * inv;
    float i_ = x1 * inv;
    float g  = x2 * inv;
    float o  = x3 * inv;
    c = f * c + i_ * fast_tanh(g);
    h = o * fast_tanh(c);
}

// ---------- main: block b owns chain b end-to-end. ----------
// Phase A (8 waves): compute this chain's 256 qx rows into LDS — block b
// reads exactly rows {t*128+b}, so the whole grid reads x once, coalesced.
// One __syncthreads. Phase B (waves 0..3): chain redundantly from LDS
// (uniform-address broadcast reads), each wave stores its quarter-row.
__global__ __launch_bounds__(512) void k_main(const float* __restrict__ x,
                                              const float* __restrict__ bq,
                                              const float* __restrict__ theta,
                                              const float* __restrict__ ws,
                                              float* __restrict__ out)
{
    __shared__ float4 qrow[T_STEPS];              // 4 KB
    const float*  M   = ws + WS_M;
    const float4* vp4 = (const float4*)(ws + WS_VP);

    const int b    = blockIdx.x;
    const int tid  = threadIdx.x;
    const int wave = tid >> 6;                    // 0..7
    const int lane = tid & 63;

    // ---- phase A: qx rows for this chain -> LDS ----
    {
        float4 m[4][4];                           // M fragment in regs
        #pragma unroll
        for (int w = 0; w < 4; w++)
            #pragma unroll
            for (int k = 0; k < 4; k++)
                m[w][k] = *(const float4*)(M + w * DIM + k * 256 + lane * 4);

        for (int t = wave; t < T_STEPS; t += 8) {
            const float4* row = (const float4*)(x + ((size_t)t * BATCH + b) * DIM);
            float a0 = 0.f, a1 = 0.f, a2 = 0.f, a3 = 0.f;
            #pragma unroll
            for (int k = 0; k < 4; k++) {
                float4 xv = row[k * 64 + lane];   // contiguous 1 KB/instr
                a0 += xv.x * m[0][k].x + xv.y * m[0][k].y + xv.z * m[0][k].z + xv.w * m[0][k].w;
                a1 += xv.x * m[1][k].x + xv.y * m[1][k].y + xv.z * m[1][k].z + xv.w * m[1][k].w;
                a2 += xv.x * m[2][k].x + xv.y * m[2][k].y + xv.z * m[2][k].z + xv.w * m[2][k].w;
                a3 += xv.x * m[3][k].x + xv.y * m[3][k].y + xv.z * m[3][k].z + xv.w * m[3][k].w;
            }
            #pragma unroll
            for (int off = 32; off; off >>= 1) {
                a0 += __shfl_xor(a0, off, 64);
                a1 += __shfl_xor(a1, off, 64);
                a2 += __shfl_xor(a2, off, 64);
                a3 += __shfl_xor(a3, off, 64);
            }
            if (lane == 0) qrow[t] = make_float4(a0, a1, a2, a3);
        }
    }
    __syncthreads();
    if (wave >= 4) return;                        // only 4 store-waves continue

    // ---- v/cb constants: reduce the 64 vpart blocks lane-parallel ----
    float4 sa = vp4[lane * 2];                    // {sv0..3}
    float4 sc = vp4[lane * 2 + 1];                // {sc0..3}
    #pragma unroll
    for (int off = 32; off; off >>= 1) {
        sa.x += __shfl_xor(sa.x, off, 64);  sa.y += __shfl_xor(sa.y, off, 64);
        sa.z += __shfl_xor(sa.z, off, 64);  sa.w += __shfl_xor(sa.w, off, 64);
        sc.x += __shfl_xor(sc.x, off, 64);  sc.y += __shfl_xor(sc.y, off, 64);
        sc.z += __shfl_xor(sc.z, off, 64);  sc.w += __shfl_xor(sc.w, off, 64);
    }
    const float v0 = sa.x, v1 = sa.y, v2 = sa.z, v3 = sa.w;
    const float b0 = sc.x + bq[0] + theta[0];
    const float b1 = sc.y + bq[1] + theta[1];
    const float b2 = sc.z + bq[2] + theta[2];
    const float b3 = sc.w + bq[3] + theta[3];

    float h = 0.f, c = 0.f;

    #define EMIT_H(tt)                                                           \
        do {                                                                     \
            vfloat4 vv = {h, h, h, h};                                           \
            __builtin_nontemporal_store(vv,                                      \
                (vfloat4*)(out + ((size_t)(tt) * BATCH + b) * DIM + wave * 256)  \
                    + lane);                                                     \
        } while (0)

    // rolling 8-deep prefetch from LDS (broadcast reads, lgkmcnt-scheduled)
    float4 q0 = qrow[0], q1 = qrow[1], q2 = qrow[2], q3 = qrow[3];
    float4 q4 = qrow[4], q5 = qrow[5], q6 = qrow[6], q7 = qrow[7];

    for (int t = 0; t < T_STEPS; t += 8) {
        float4 n0, n1, n2, n3, n4, n5, n6, n7;
        if (t + 8 < T_STEPS) {
            n0 = qrow[t + 8];  n1 = qrow[t + 9];
            n2 = qrow[t + 10]; n3 = qrow[t + 11];
            n4 = qrow[t + 12]; n5 = qrow[t + 13];
            n6 = qrow[t + 14]; n7 = qrow[t + 15];
        }
        rec_step(q0, b0, b1, b2, b3, v0, v1, v2, v3, h, c); EMIT_H(t + 0);
        rec_step(q1, b0, b1, b2, b3, v0, v1, v2, v3, h, c); EMIT_H(t + 1);
        rec_step(q2, b0, b1, b2, b3, v0, v1, v2, v3, h, c); EMIT_H(t + 2);
        rec_step(q3, b0, b1, b2, b3, v0, v1, v2, v3, h, c); EMIT_H(t + 3);
        rec_step(q4, b0, b1, b2, b3, v0, v1, v2, v3, h, c); EMIT_H(t + 4);
        rec_step(q5, b0, b1, b2, b3, v0, v1, v2, v3, h, c); EMIT_H(t + 5);
        rec_step(q6, b0, b1, b2, b3, v0, v1, v2, v3, h, c); EMIT_H(t + 6);
        rec_step(q7, b0, b1, b2, b3, v0, v1, v2, v3, h, c); EMIT_H(t + 7);
        q0 = n0; q1 = n1; q2 = n2; q3 = n3; q4 = n4; q5 = n5; q6 = n6; q7 = n7;
    }
    #undef EMIT_H

    // tail rows: hx broadcast = final h; cx broadcast = final c (quarter rows)
    vfloat4 hv = {h, h, h, h};
    vfloat4 cv = {c, c, c, c};
    __builtin_nontemporal_store(hv,
        (vfloat4*)(out + ((size_t)NROWS + b) * DIM + wave * 256) + lane);
    __builtin_nontemporal_store(cv,
        (vfloat4*)(out + ((size_t)NROWS + BATCH + b) * DIM + wave * 256) + lane);
}

extern "C" void kernel_launch(void* const* d_in, const int* in_sizes, int n_in,
                              void* d_out, int out_size, void* d_ws, size_t ws_size,
                              hipStream_t stream) {
    const float* inputs = (const float*)d_in[0];
    const float* Wi     = (const float*)d_in[1];
    const float* bi     = (const float*)d_in[2];
    const float* Wh     = (const float*)d_in[3];
    const float* bh     = (const float*)d_in[4];
    const float* Wq     = (const float*)d_in[5];
    const float* bq     = (const float*)d_in[6];
    const float* theta  = (const float*)d_in[7];
    float* out = (float*)d_out;
    float* ws  = (float*)d_ws;

    float* M     = ws + WS_M;
    float* vpart = ws + WS_VP;

    k_prep<<<80,    256, 0, stream>>>(Wi, Wh, bi, bh, Wq, M, vpart);
    k_main<<<BATCH, 512, 0, stream>>>(inputs, bq, theta, ws, out);
}